// Round 8
// baseline (53.772 us; speedup 1.0000x reference)
//
#include <hip/hip_runtime.h>
#include <hip/hip_bf16.h>
#include <math.h>

#define BB 8
#define SS 2048
#define HH 768
#define NN 512
#define MAXW 30
#define SPW 8            // spans (waves) per block
#define CH  4            // rows per chunk (union-window sweep)

// ---- Kernel A: per-example counting sort of spans by start (parallel scan) ----
__global__ __launch_bounds__(256) void sort_spans_kernel(
    const int* __restrict__ starts,   // (B, N)
    int*       __restrict__ order)    // (B, N): order[b*N + rank] = span idx
{
    const int b   = blockIdx.x;
    const int tid = threadIdx.x;
    __shared__ int hist[SS];
    __shared__ int wsum[4];

    for (int i = tid; i < SS; i += 256) hist[i] = 0;
    __syncthreads();

    const int* st = starts + b * NN;
    for (int n = tid; n < NN; n += 256) atomicAdd(&hist[st[n]], 1);
    __syncthreads();

    const int base = tid * 8;
    int cnt[8]; int s = 0;
    #pragma unroll
    for (int k = 0; k < 8; ++k) { cnt[k] = hist[base + k]; s += cnt[k]; }

    const int lane = tid & 63, wv = tid >> 6;
    int v = s;
    #pragma unroll
    for (int off = 1; off < 64; off <<= 1) {
        int u = __shfl_up(v, off);
        if (lane >= off) v += u;
    }
    if (lane == 63) wsum[wv] = v;
    __syncthreads();
    int wbase = 0;
    #pragma unroll
    for (int k = 0; k < 4; ++k) wbase += (k < wv) ? wsum[k] : 0;

    int excl = wbase + v - s;
    #pragma unroll
    for (int k = 0; k < 8; ++k) { int c = cnt[k]; hist[base + k] = excl; excl += c; }
    __syncthreads();

    for (int n = tid; n < NN; n += 256) {
        int pos = atomicAdd(&hist[st[n]], 1);
        order[b * NN + pos] = n;
    }
}

// ---- Kernel B: 8 consecutive sorted spans per block (wave each). All waves
//      sweep the block's UNION token window in lockstep chunks of CH rows so
//      overlapping rows dedup through L1/MSHR. Valid-only loads; chunk-max
//      online softmax; start/end rows emitted in the same pass.
__global__ __launch_bounds__(512, 4) void span_union_kernel(
    const float* __restrict__ emb,      // (B, S, H)
    const float* __restrict__ w,        // (H)
    const float* __restrict__ bias,     // (1)
    const int*   __restrict__ starts,   // (B, N)
    const int*   __restrict__ lengths,  // (B, N)
    const int*   __restrict__ order,    // (B, N) or nullptr
    float*       __restrict__ out)      // (B, N, 3H)
{
    const int tid  = threadIdx.x;
    const int wv   = tid >> 6;           // 0..7
    const int lane = tid & 63;
    const int bi   = blockIdx.x & 7;     // example <-> XCD
    const int g    = (int)blockIdx.x >> 3;
    const int rank = g * SPW + wv;
    const int n    = order ? order[bi * NN + rank] : rank;
    const int span = bi * NN + n;

    const int start = starts[span];
    const int len   = lengths[span];
    const int end   = start + len;       // inclusive

    __shared__ int s_lo[SPW], s_hi[SPW];
    if (lane == 0) { s_lo[wv] = start; s_hi[wv] = end; }
    __syncthreads();
    int wlo = s_lo[0], whi = s_hi[0];
    #pragma unroll
    for (int k = 1; k < SPW; ++k) { wlo = min(wlo, s_lo[k]); whi = max(whi, s_hi[k]); }

    const float* ebase = emb + (size_t)bi * SS * HH;
    const int h0 = lane * 4;
    float* orow = out + (size_t)span * (3 * HH);

    const float4 w0 = *reinterpret_cast<const float4*>(w + h0);
    const float4 w1 = *reinterpret_cast<const float4*>(w + h0 + 256);
    const float4 w2 = *reinterpret_cast<const float4*>(w + h0 + 512);
    const float bb = bias[0];

    float m = -INFINITY, ssum = 0.f;
    float4 a0 = make_float4(0.f, 0.f, 0.f, 0.f), a1 = a0, a2 = a0;

    const int nch = (whi - wlo) / CH + 1;      // ceil(window / CH), block-uniform

    for (int c = 0; c < nch; ++c) {
        const int clo = wlo + c * CH;

        // ---- load my valid rows of this chunk (wave-uniform validity) ----
        float4 r0[CH], r1[CH], r2[CH];
        bool val[CH];
        #pragma unroll
        for (int k = 0; k < CH; ++k) {
            const int t = clo + k;
            val[k] = (t >= start) && (t <= end);
            if (val[k]) {
                const float* rp = ebase + (size_t)t * HH + h0;
                r0[k] = *reinterpret_cast<const float4*>(rp);
                r1[k] = *reinterpret_cast<const float4*>(rp + 256);
                r2[k] = *reinterpret_cast<const float4*>(rp + 512);
            }
        }

        // ---- partial dots (independent chains; invalid -> 0) ----
        float d[CH];
        #pragma unroll
        for (int k = 0; k < CH; ++k) {
            d[k] = val[k]
                 ? (r0[k].x * w0.x + r0[k].y * w0.y + r0[k].z * w0.z + r0[k].w * w0.w
                  + r1[k].x * w1.x + r1[k].y * w1.y + r1[k].z * w1.z + r1[k].w * w1.w
                  + r2[k].x * w2.x + r2[k].y * w2.y + r2[k].z * w2.z + r2[k].w * w2.w)
                 : 0.f;
        }

        // ---- interleaved butterfly reduces ----
        #pragma unroll
        for (int off = 32; off; off >>= 1) {
            #pragma unroll
            for (int k = 0; k < CH; ++k) d[k] += __shfl_xor(d[k], off);
        }
        #pragma unroll
        for (int k = 0; k < CH; ++k)
            d[k] = val[k] ? (d[k] + bb) : -INFINITY;

        // ---- chunk-max rescale (wave-uniform) ----
        float cmax = d[0];
        #pragma unroll
        for (int k = 1; k < CH; ++k) cmax = fmaxf(cmax, d[k]);
        if (cmax > m) {                          // false when chunk fully invalid
            const float cc = __expf(m - cmax);   // first valid chunk: exp(-inf)=0
            ssum *= cc;
            a0.x *= cc; a0.y *= cc; a0.z *= cc; a0.w *= cc;
            a1.x *= cc; a1.y *= cc; a1.z *= cc; a1.w *= cc;
            a2.x *= cc; a2.y *= cc; a2.z *= cc; a2.w *= cc;
            m = cmax;
        }

        // ---- valid-only accumulate + start/end emission ----
        #pragma unroll
        for (int k = 0; k < CH; ++k) {
            if (val[k]) {
                const float pt = __expf(d[k] - m);
                ssum += pt;
                a0.x += pt * r0[k].x; a0.y += pt * r0[k].y; a0.z += pt * r0[k].z; a0.w += pt * r0[k].w;
                a1.x += pt * r1[k].x; a1.y += pt * r1[k].y; a1.z += pt * r1[k].z; a1.w += pt * r1[k].w;
                a2.x += pt * r2[k].x; a2.y += pt * r2[k].y; a2.z += pt * r2[k].z; a2.w += pt * r2[k].w;

                const int t = clo + k;
                if (t == start) {
                    *reinterpret_cast<float4*>(orow + h0)       = r0[k];
                    *reinterpret_cast<float4*>(orow + h0 + 256) = r1[k];
                    *reinterpret_cast<float4*>(orow + h0 + 512) = r2[k];
                }
                if (t == end) {
                    *reinterpret_cast<float4*>(orow + HH + h0)       = r0[k];
                    *reinterpret_cast<float4*>(orow + HH + h0 + 256) = r1[k];
                    *reinterpret_cast<float4*>(orow + HH + h0 + 512) = r2[k];
                }
            }
        }

        __syncthreads();                         // keep waves lockstep for dedup
    }

    const float inv = 1.f / ssum;
    a0.x *= inv; a0.y *= inv; a0.z *= inv; a0.w *= inv;
    a1.x *= inv; a1.y *= inv; a1.z *= inv; a1.w *= inv;
    a2.x *= inv; a2.y *= inv; a2.z *= inv; a2.w *= inv;
    *reinterpret_cast<float4*>(orow + 2 * HH + h0)       = a0;
    *reinterpret_cast<float4*>(orow + 2 * HH + h0 + 256) = a1;
    *reinterpret_cast<float4*>(orow + 2 * HH + h0 + 512) = a2;
}

extern "C" void kernel_launch(void* const* d_in, const int* in_sizes, int n_in,
                              void* d_out, int out_size, void* d_ws, size_t ws_size,
                              hipStream_t stream) {
    const float* emb     = (const float*)d_in[0];
    const float* w       = (const float*)d_in[1];
    const float* bias    = (const float*)d_in[2];
    const int*   starts  = (const int*)d_in[3];
    const int*   lengths = (const int*)d_in[4];
    float*       out     = (float*)d_out;

    int* order = nullptr;
    if (ws_size >= (size_t)(BB * NN * sizeof(int))) {
        order = (int*)d_ws;
        sort_spans_kernel<<<dim3(BB), dim3(256), 0, stream>>>(starts, order);
    }

    span_union_kernel<<<dim3(BB * NN / SPW), dim3(512), 0, stream>>>(
        emb, w, bias, starts, lengths, order, out);
}

// Round 9
// 35.507 us; speedup vs baseline: 1.5144x; 1.5144x over previous
//
#include <hip/hip_runtime.h>
#include <hip/hip_bf16.h>
#include <math.h>

#define BB 8
#define SS 2048
#define HH 768
#define NN 512
#define MAXW 30

// ---- Kernel A: per-example counting sort of spans by start (parallel scan) ----
__global__ __launch_bounds__(256) void sort_spans_kernel(
    const int* __restrict__ starts,   // (B, N)
    int*       __restrict__ order)    // (B, N): order[b*N + rank] = span idx
{
    const int b   = blockIdx.x;
    const int tid = threadIdx.x;
    __shared__ int hist[SS];
    __shared__ int wsum[4];

    for (int i = tid; i < SS; i += 256) hist[i] = 0;
    __syncthreads();

    const int* st = starts + b * NN;
    for (int n = tid; n < NN; n += 256) atomicAdd(&hist[st[n]], 1);
    __syncthreads();

    const int base = tid * 8;
    int cnt[8]; int s = 0;
    #pragma unroll
    for (int k = 0; k < 8; ++k) { cnt[k] = hist[base + k]; s += cnt[k]; }

    const int lane = tid & 63, wv = tid >> 6;
    int v = s;
    #pragma unroll
    for (int off = 1; off < 64; off <<= 1) {
        int u = __shfl_up(v, off);
        if (lane >= off) v += u;
    }
    if (lane == 63) wsum[wv] = v;
    __syncthreads();
    int wbase = 0;
    #pragma unroll
    for (int k = 0; k < 4; ++k) wbase += (k < wv) ? wsum[k] : 0;

    int excl = wbase + v - s;
    #pragma unroll
    for (int k = 0; k < 8; ++k) { int c = cnt[k]; hist[base + k] = excl; excl += c; }
    __syncthreads();

    for (int n = tid; n < NN; n += 256) {
        int pos = atomicAdd(&hist[st[n]], 1);
        order[b * NN + pos] = n;
    }
}

// ---- Kernel B: TWO consecutive sorted spans per wave, swept over the union
//      of their token windows (rows in overlap are loaded & scored ONCE).
//      Two independent online-softmax states; 2-deep register prefetch.
//      No LDS data plane, no extra barriers.
__global__ __launch_bounds__(256) void span_pair_kernel(
    const float* __restrict__ emb,      // (B, S, H)
    const float* __restrict__ w,        // (H)
    const float* __restrict__ bias,     // (1)
    const int*   __restrict__ starts,   // (B, N)
    const int*   __restrict__ lengths,  // (B, N)
    const int*   __restrict__ order,    // (B, N) or nullptr
    float*       __restrict__ out)      // (B, N, 3H)
{
    const int tid  = threadIdx.x;
    const int wv   = tid >> 6;            // 0..3
    const int lane = tid & 63;
    const int bi   = blockIdx.x & 7;      // example <-> XCD
    const int g    = (int)blockIdx.x >> 3;     // 0..63 per example
    const int pr   = g * 4 + wv;               // pair index 0..255
    const int rkA  = pr * 2, rkB = rkA + 1;
    const int nA   = order ? order[bi * NN + rkA] : rkA;
    const int nB   = order ? order[bi * NN + rkB] : rkB;
    const int spanA = bi * NN + nA;
    const int spanB = bi * NN + nB;

    const int startA = starts[spanA], lenA = lengths[spanA], endA = startA + lenA;
    const int startB = starts[spanB], lenB = lengths[spanB], endB = startB + lenB;
    const int lo = min(startA, startB);
    const int hi = max(endA, endB);

    const float* ebase = emb + (size_t)bi * SS * HH;
    const int h0 = lane * 4;
    float* orA = out + (size_t)spanA * (3 * HH);
    float* orB = out + (size_t)spanB * (3 * HH);

    const float4 w0 = *reinterpret_cast<const float4*>(w + h0);
    const float4 w1 = *reinterpret_cast<const float4*>(w + h0 + 256);
    const float4 w2 = *reinterpret_cast<const float4*>(w + h0 + 512);
    const float bb = bias[0];

    float mA = -INFINITY, sA = 0.f;
    float4 aA0 = make_float4(0.f,0.f,0.f,0.f), aA1 = aA0, aA2 = aA0;
    float mB = -INFINITY, sB = 0.f;
    float4 aB0 = aA0, aB1 = aA0, aB2 = aA0;

    // ---- 2-deep register prefetch pipeline over [lo, hi] ----
    const float* p0 = ebase + (size_t)lo * HH + h0;
    float4 c0 = *reinterpret_cast<const float4*>(p0);
    float4 c1 = *reinterpret_cast<const float4*>(p0 + 256);
    float4 c2 = *reinterpret_cast<const float4*>(p0 + 512);
    const float* p1 = ebase + (size_t)min(lo + 1, hi) * HH + h0;
    float4 x0 = *reinterpret_cast<const float4*>(p1);
    float4 x1 = *reinterpret_cast<const float4*>(p1 + 256);
    float4 x2 = *reinterpret_cast<const float4*>(p1 + 512);

    for (int t = lo; t <= hi; ++t) {
        // issue load for t+2 (clamped; redundant tail loads are L1-hot)
        const float* p2 = ebase + (size_t)min(t + 2, hi) * HH + h0;
        float4 y0 = *reinterpret_cast<const float4*>(p2);
        float4 y1 = *reinterpret_cast<const float4*>(p2 + 256);
        float4 y2 = *reinterpret_cast<const float4*>(p2 + 512);

        // shared score: dot(row, w) reduced across the wave
        float d = c0.x * w0.x + c0.y * w0.y + c0.z * w0.z + c0.w * w0.w
                + c1.x * w1.x + c1.y * w1.y + c1.z * w1.z + c1.w * w1.w
                + c2.x * w2.x + c2.y * w2.y + c2.z * w2.z + c2.w * w2.w;
        #pragma unroll
        for (int off = 32; off; off >>= 1) d += __shfl_xor(d, off);
        d += bb;

        // ---- span A update (wave-uniform predicate) ----
        if (t >= startA && t <= endA) {
            if (d > mA) {
                const float c = __expf(mA - d);      // first: exp(-inf)=0
                sA *= c;
                aA0.x *= c; aA0.y *= c; aA0.z *= c; aA0.w *= c;
                aA1.x *= c; aA1.y *= c; aA1.z *= c; aA1.w *= c;
                aA2.x *= c; aA2.y *= c; aA2.z *= c; aA2.w *= c;
                mA = d;
            }
            const float pt = __expf(d - mA);
            sA += pt;
            aA0.x += pt * c0.x; aA0.y += pt * c0.y; aA0.z += pt * c0.z; aA0.w += pt * c0.w;
            aA1.x += pt * c1.x; aA1.y += pt * c1.y; aA1.z += pt * c1.z; aA1.w += pt * c1.w;
            aA2.x += pt * c2.x; aA2.y += pt * c2.y; aA2.z += pt * c2.z; aA2.w += pt * c2.w;
            if (t == startA) {
                *reinterpret_cast<float4*>(orA + h0)       = c0;
                *reinterpret_cast<float4*>(orA + h0 + 256) = c1;
                *reinterpret_cast<float4*>(orA + h0 + 512) = c2;
            }
            if (t == endA) {
                *reinterpret_cast<float4*>(orA + HH + h0)       = c0;
                *reinterpret_cast<float4*>(orA + HH + h0 + 256) = c1;
                *reinterpret_cast<float4*>(orA + HH + h0 + 512) = c2;
            }
        }

        // ---- span B update ----
        if (t >= startB && t <= endB) {
            if (d > mB) {
                const float c = __expf(mB - d);
                sB *= c;
                aB0.x *= c; aB0.y *= c; aB0.z *= c; aB0.w *= c;
                aB1.x *= c; aB1.y *= c; aB1.z *= c; aB1.w *= c;
                aB2.x *= c; aB2.y *= c; aB2.z *= c; aB2.w *= c;
                mB = d;
            }
            const float pt = __expf(d - mB);
            sB += pt;
            aB0.x += pt * c0.x; aB0.y += pt * c0.y; aB0.z += pt * c0.z; aB0.w += pt * c0.w;
            aB1.x += pt * c1.x; aB1.y += pt * c1.y; aB1.z += pt * c1.z; aB1.w += pt * c1.w;
            aB2.x += pt * c2.x; aB2.y += pt * c2.y; aB2.z += pt * c2.z; aB2.w += pt * c2.w;
            if (t == startB) {
                *reinterpret_cast<float4*>(orB + h0)       = c0;
                *reinterpret_cast<float4*>(orB + h0 + 256) = c1;
                *reinterpret_cast<float4*>(orB + h0 + 512) = c2;
            }
            if (t == endB) {
                *reinterpret_cast<float4*>(orB + HH + h0)       = c0;
                *reinterpret_cast<float4*>(orB + HH + h0 + 256) = c1;
                *reinterpret_cast<float4*>(orB + HH + h0 + 512) = c2;
            }
        }

        // rotate pipeline
        c0 = x0; c1 = x1; c2 = x2;
        x0 = y0; x1 = y1; x2 = y2;
    }

    const float invA = 1.f / sA;
    aA0.x *= invA; aA0.y *= invA; aA0.z *= invA; aA0.w *= invA;
    aA1.x *= invA; aA1.y *= invA; aA1.z *= invA; aA1.w *= invA;
    aA2.x *= invA; aA2.y *= invA; aA2.z *= invA; aA2.w *= invA;
    *reinterpret_cast<float4*>(orA + 2 * HH + h0)       = aA0;
    *reinterpret_cast<float4*>(orA + 2 * HH + h0 + 256) = aA1;
    *reinterpret_cast<float4*>(orA + 2 * HH + h0 + 512) = aA2;

    const float invB = 1.f / sB;
    aB0.x *= invB; aB0.y *= invB; aB0.z *= invB; aB0.w *= invB;
    aB1.x *= invB; aB1.y *= invB; aB1.z *= invB; aB1.w *= invB;
    aB2.x *= invB; aB2.y *= invB; aB2.z *= invB; aB2.w *= invB;
    *reinterpret_cast<float4*>(orB + 2 * HH + h0)       = aB0;
    *reinterpret_cast<float4*>(orB + 2 * HH + h0 + 256) = aB1;
    *reinterpret_cast<float4*>(orB + 2 * HH + h0 + 512) = aB2;
}

extern "C" void kernel_launch(void* const* d_in, const int* in_sizes, int n_in,
                              void* d_out, int out_size, void* d_ws, size_t ws_size,
                              hipStream_t stream) {
    const float* emb     = (const float*)d_in[0];
    const float* w       = (const float*)d_in[1];
    const float* bias    = (const float*)d_in[2];
    const int*   starts  = (const int*)d_in[3];
    const int*   lengths = (const int*)d_in[4];
    float*       out     = (float*)d_out;

    int* order = nullptr;
    if (ws_size >= (size_t)(BB * NN * sizeof(int))) {
        order = (int*)d_ws;
        sort_spans_kernel<<<dim3(BB), dim3(256), 0, stream>>>(starts, order);
    }

    // 2 spans per wave, 4 waves per block -> B*N/8 blocks
    span_pair_kernel<<<dim3(BB * NN / 8), dim3(256), 0, stream>>>(
        emb, w, bias, starts, lengths, order, out);
}

// Round 10
// 32.378 us; speedup vs baseline: 1.6608x; 1.0967x over previous
//
#include <hip/hip_runtime.h>
#include <hip/hip_bf16.h>
#include <math.h>

#define BB 8
#define SS 2048
#define HH 768
#define NN 512
#define MAXW 30

// fp32 -> bf16 (RNE) as raw ushort
static __device__ __forceinline__ unsigned short f2bf(float f) {
    union { float f; unsigned int u; } v; v.f = f;
    unsigned int r = (v.u + 0x7FFFu + ((v.u >> 16) & 1u)) >> 16;
    return (unsigned short)r;
}
static __device__ __forceinline__ float bflo(unsigned int u) {
    union { unsigned int u; float f; } v; v.u = u << 16; return v.f;
}
static __device__ __forceinline__ float bfhi(unsigned int u) {
    union { unsigned int u; float f; } v; v.u = u & 0xFFFF0000u; return v.f;
}

// ---- Kernel 1: streaming convert emb fp32 -> bf16 copy + token-score GEMV.
//      XCD-pinned by example (blockIdx&7). 1024 blocks x 256 thr; 16 rows/block.
__global__ __launch_bounds__(256) void conv_kernel(
    const float* __restrict__ emb,      // (B, S, H)
    const float* __restrict__ w,        // (H)
    const float* __restrict__ bias,     // (1)
    unsigned short* __restrict__ ebf,   // (B, S, H) bf16 out
    float*       __restrict__ scores)   // (B*S)
{
    const int tid  = threadIdx.x;
    const int wv   = tid >> 6;
    const int lane = tid & 63;
    const int bi   = blockIdx.x & 7;            // example <-> XCD
    const int g    = (int)blockIdx.x >> 3;      // 0..127
    const int t0   = g * 16 + wv * 4;           // 4 rows per wave

    const float* eb = emb + (size_t)bi * SS * HH;
    unsigned short* ob = ebf + (size_t)bi * SS * HH;

    const int h0 = lane * 4;
    const float4 w0 = *reinterpret_cast<const float4*>(w + h0);
    const float4 w1 = *reinterpret_cast<const float4*>(w + h0 + 256);
    const float4 w2 = *reinterpret_cast<const float4*>(w + h0 + 512);
    const float bb = bias[0];

    #pragma unroll
    for (int k = 0; k < 4; ++k) {
        const int t = t0 + k;
        const float* rp = eb + (size_t)t * HH;
        float4 v0 = *reinterpret_cast<const float4*>(rp + h0);
        float4 v1 = *reinterpret_cast<const float4*>(rp + h0 + 256);
        float4 v2 = *reinterpret_cast<const float4*>(rp + h0 + 512);

        float d = v0.x * w0.x + v0.y * w0.y + v0.z * w0.z + v0.w * w0.w
                + v1.x * w1.x + v1.y * w1.y + v1.z * w1.z + v1.w * w1.w
                + v2.x * w2.x + v2.y * w2.y + v2.z * w2.z + v2.w * w2.w;
        #pragma unroll
        for (int off = 32; off; off >>= 1) d += __shfl_xor(d, off);

        // pack 12 floats -> 3 x uint2 (4 bf16 each), same h layout
        uint2 pa, pb, pc;
        pa.x = (unsigned)f2bf(v0.x) | ((unsigned)f2bf(v0.y) << 16);
        pa.y = (unsigned)f2bf(v0.z) | ((unsigned)f2bf(v0.w) << 16);
        pb.x = (unsigned)f2bf(v1.x) | ((unsigned)f2bf(v1.y) << 16);
        pb.y = (unsigned)f2bf(v1.z) | ((unsigned)f2bf(v1.w) << 16);
        pc.x = (unsigned)f2bf(v2.x) | ((unsigned)f2bf(v2.y) << 16);
        pc.y = (unsigned)f2bf(v2.z) | ((unsigned)f2bf(v2.w) << 16);

        unsigned short* op = ob + (size_t)t * HH;
        *reinterpret_cast<uint2*>(op + h0)       = pa;
        *reinterpret_cast<uint2*>(op + h0 + 256) = pb;
        *reinterpret_cast<uint2*>(op + h0 + 512) = pc;

        if (lane == 0) scores[bi * SS + t] = d + bb;
    }
}

// ---- Kernel 2: one wave per span. Softmax from precomputed scores (one
//      butterfly pair), then a single bf16-row sweep: 1 shfl + 12 FMA per row.
__global__ __launch_bounds__(256) void span_bf16_kernel(
    const unsigned short* __restrict__ ebf,   // (B, S, H) bf16
    const float* __restrict__ scores,         // (B*S)
    const int*   __restrict__ starts,         // (B, N)
    const int*   __restrict__ lengths,        // (B, N)
    float*       __restrict__ out)            // (B, N, 3H)
{
    const int tid  = threadIdx.x;
    const int wv   = tid >> 6;
    const int lane = tid & 63;
    const int bi   = blockIdx.x & 7;          // example <-> XCD
    const int rank = ((int)blockIdx.x >> 3) * 4 + wv;
    const int span = bi * NN + rank;

    const int start = starts[span];
    const int len   = lengths[span];          // valid t = 0..len (<= 29)

    // ---- softmax up-front: lane t holds p_t ----
    float sc = (lane <= len) ? scores[bi * SS + start + lane] : -INFINITY;
    float m = sc;
    #pragma unroll
    for (int off = 32; off; off >>= 1) m = fmaxf(m, __shfl_xor(m, off));
    float e = (lane <= len) ? __expf(sc - m) : 0.f;
    float sum = e;
    #pragma unroll
    for (int off = 32; off; off >>= 1) sum += __shfl_xor(sum, off);
    const float p = e / sum;

    const unsigned short* rb = ebf + (size_t)bi * SS * HH + (size_t)start * HH;
    const int h0 = lane * 4;
    float* orow = out + (size_t)span * (3 * HH);

    float4 a0 = make_float4(0.f, 0.f, 0.f, 0.f), a1 = a0, a2 = a0;

    // 2-deep prefetch pipeline (clamped; redundant tail loads are L1-hot)
    const unsigned short* rp0 = rb;
    uint2 cA = *reinterpret_cast<const uint2*>(rp0 + h0);
    uint2 cB = *reinterpret_cast<const uint2*>(rp0 + h0 + 256);
    uint2 cC = *reinterpret_cast<const uint2*>(rp0 + h0 + 512);
    const unsigned short* rp1 = rb + (size_t)min(1, len) * HH;
    uint2 xA = *reinterpret_cast<const uint2*>(rp1 + h0);
    uint2 xB = *reinterpret_cast<const uint2*>(rp1 + h0 + 256);
    uint2 xC = *reinterpret_cast<const uint2*>(rp1 + h0 + 512);

    for (int t = 0; t <= len; ++t) {
        const unsigned short* rp2 = rb + (size_t)min(t + 2, len) * HH;
        uint2 yA = *reinterpret_cast<const uint2*>(rp2 + h0);
        uint2 yB = *reinterpret_cast<const uint2*>(rp2 + h0 + 256);
        uint2 yC = *reinterpret_cast<const uint2*>(rp2 + h0 + 512);

        const float pt = __shfl(p, t);

        float4 f0, f1, f2;
        f0.x = bflo(cA.x); f0.y = bfhi(cA.x); f0.z = bflo(cA.y); f0.w = bfhi(cA.y);
        f1.x = bflo(cB.x); f1.y = bfhi(cB.x); f1.z = bflo(cB.y); f1.w = bfhi(cB.y);
        f2.x = bflo(cC.x); f2.y = bfhi(cC.x); f2.z = bflo(cC.y); f2.w = bfhi(cC.y);

        a0.x += pt * f0.x; a0.y += pt * f0.y; a0.z += pt * f0.z; a0.w += pt * f0.w;
        a1.x += pt * f1.x; a1.y += pt * f1.y; a1.z += pt * f1.z; a1.w += pt * f1.w;
        a2.x += pt * f2.x; a2.y += pt * f2.y; a2.z += pt * f2.z; a2.w += pt * f2.w;

        if (t == 0) {                    // start row
            *reinterpret_cast<float4*>(orow + h0)       = f0;
            *reinterpret_cast<float4*>(orow + h0 + 256) = f1;
            *reinterpret_cast<float4*>(orow + h0 + 512) = f2;
        }
        if (t == len) {                  // end row
            *reinterpret_cast<float4*>(orow + HH + h0)       = f0;
            *reinterpret_cast<float4*>(orow + HH + h0 + 256) = f1;
            *reinterpret_cast<float4*>(orow + HH + h0 + 512) = f2;
        }

        cA = xA; cB = xB; cC = xC;
        xA = yA; xB = yB; xC = yC;
    }

    *reinterpret_cast<float4*>(orow + 2 * HH + h0)       = a0;
    *reinterpret_cast<float4*>(orow + 2 * HH + h0 + 256) = a1;
    *reinterpret_cast<float4*>(orow + 2 * HH + h0 + 512) = a2;
}

// ---- Fallback (tiny ws): R4's fused fp32 single-pass kernel ----
__global__ __launch_bounds__(256) void span_fused_fp32_kernel(
    const float* __restrict__ emb, const float* __restrict__ w,
    const float* __restrict__ bias, const int* __restrict__ starts,
    const int* __restrict__ lengths, float* __restrict__ out)
{
    const int tid  = threadIdx.x;
    const int wv   = tid >> 6;
    const int lane = tid & 63;
    const int bi   = blockIdx.x & 7;
    const int rank = ((int)blockIdx.x >> 3) * 4 + wv;
    const int span = bi * NN + rank;
    const int start = starts[span];
    const int len   = lengths[span];

    const float* ebase = emb + (size_t)bi * SS * HH + (size_t)start * HH;
    const int h0 = lane * 4;
    float* orow = out + (size_t)span * (3 * HH);

    const float4 w0 = *reinterpret_cast<const float4*>(w + h0);
    const float4 w1 = *reinterpret_cast<const float4*>(w + h0 + 256);
    const float4 w2 = *reinterpret_cast<const float4*>(w + h0 + 512);
    const float bb = bias[0];

    float m = -INFINITY, ssum = 0.f;
    float4 a0 = make_float4(0.f, 0.f, 0.f, 0.f), a1 = a0, a2 = a0;

    const float* row = ebase;
    float4 v0 = *reinterpret_cast<const float4*>(row + h0);
    float4 v1 = *reinterpret_cast<const float4*>(row + h0 + 256);
    float4 v2 = *reinterpret_cast<const float4*>(row + h0 + 512);

    for (int t = 0; t <= len; ++t) {
        float4 n0, n1, n2;
        if (t < len) {
            const float* nr = row + HH;
            n0 = *reinterpret_cast<const float4*>(nr + h0);
            n1 = *reinterpret_cast<const float4*>(nr + h0 + 256);
            n2 = *reinterpret_cast<const float4*>(nr + h0 + 512);
        }
        float d = v0.x * w0.x + v0.y * w0.y + v0.z * w0.z + v0.w * w0.w
                + v1.x * w1.x + v1.y * w1.y + v1.z * w1.z + v1.w * w1.w
                + v2.x * w2.x + v2.y * w2.y + v2.z * w2.z + v2.w * w2.w;
        #pragma unroll
        for (int off = 32; off; off >>= 1) d += __shfl_xor(d, off);
        d += bb;
        if (d > m) {
            const float c = __expf(m - d);
            ssum *= c;
            a0.x *= c; a0.y *= c; a0.z *= c; a0.w *= c;
            a1.x *= c; a1.y *= c; a1.z *= c; a1.w *= c;
            a2.x *= c; a2.y *= c; a2.z *= c; a2.w *= c;
            m = d;
        }
        const float pt = __expf(d - m);
        ssum += pt;
        a0.x += pt * v0.x; a0.y += pt * v0.y; a0.z += pt * v0.z; a0.w += pt * v0.w;
        a1.x += pt * v1.x; a1.y += pt * v1.y; a1.z += pt * v1.z; a1.w += pt * v1.w;
        a2.x += pt * v2.x; a2.y += pt * v2.y; a2.z += pt * v2.z; a2.w += pt * v2.w;
        if (t == 0) {
            *reinterpret_cast<float4*>(orow + h0)       = v0;
            *reinterpret_cast<float4*>(orow + h0 + 256) = v1;
            *reinterpret_cast<float4*>(orow + h0 + 512) = v2;
        }
        if (t == len) {
            *reinterpret_cast<float4*>(orow + HH + h0)       = v0;
            *reinterpret_cast<float4*>(orow + HH + h0 + 256) = v1;
            *reinterpret_cast<float4*>(orow + HH + h0 + 512) = v2;
        }
        v0 = n0; v1 = n1; v2 = n2;
        row += HH;
    }
    const float inv = 1.f / ssum;
    a0.x *= inv; a0.y *= inv; a0.z *= inv; a0.w *= inv;
    a1.x *= inv; a1.y *= inv; a1.z *= inv; a1.w *= inv;
    a2.x *= inv; a2.y *= inv; a2.z *= inv; a2.w *= inv;
    *reinterpret_cast<float4*>(orow + 2 * HH + h0)       = a0;
    *reinterpret_cast<float4*>(orow + 2 * HH + h0 + 256) = a1;
    *reinterpret_cast<float4*>(orow + 2 * HH + h0 + 512) = a2;
}

extern "C" void kernel_launch(void* const* d_in, const int* in_sizes, int n_in,
                              void* d_out, int out_size, void* d_ws, size_t ws_size,
                              hipStream_t stream) {
    const float* emb     = (const float*)d_in[0];
    const float* w       = (const float*)d_in[1];
    const float* bias    = (const float*)d_in[2];
    const int*   starts  = (const int*)d_in[3];
    const int*   lengths = (const int*)d_in[4];
    float*       out     = (float*)d_out;

    const size_t ebf_bytes    = (size_t)BB * SS * HH * sizeof(unsigned short);
    const size_t scores_bytes = (size_t)BB * SS * sizeof(float);

    if (ws_size >= ebf_bytes + scores_bytes) {
        unsigned short* ebf = (unsigned short*)d_ws;
        float* scores = (float*)((char*)d_ws + ebf_bytes);

        conv_kernel<<<dim3(1024), dim3(256), 0, stream>>>(emb, w, bias, ebf, scores);
        span_bf16_kernel<<<dim3(BB * NN / 4), dim3(256), 0, stream>>>(
            ebf, scores, starts, lengths, out);
    } else {
        span_fused_fp32_kernel<<<dim3(BB * NN / 4), dim3(256), 0, stream>>>(
            emb, w, bias, starts, lengths, out);
    }
}

// Round 11
// 31.145 us; speedup vs baseline: 1.7265x; 1.0396x over previous
//
#include <hip/hip_runtime.h>
#include <hip/hip_bf16.h>
#include <math.h>

#define BB 8
#define SS 2048
#define HH 768
#define NN 512
#define MAXW 30

typedef float f32x4 __attribute__((ext_vector_type(4)));

// fp32 -> bf16 (RNE) as raw ushort
static __device__ __forceinline__ unsigned short f2bf(float f) {
    union { float f; unsigned int u; } v; v.f = f;
    unsigned int r = (v.u + 0x7FFFu + ((v.u >> 16) & 1u)) >> 16;
    return (unsigned short)r;
}
static __device__ __forceinline__ float bflo(unsigned int u) {
    union { unsigned int u; float f; } v; v.u = u << 16; return v.f;
}
static __device__ __forceinline__ float bfhi(unsigned int u) {
    union { unsigned int u; float f; } v; v.u = u & 0xFFFF0000u; return v.f;
}

// ---- Kernel 1: conv (1024 blocks) + fused per-example counting sort (8 blocks).
//      conv: fp32 rows (nontemporal) -> bf16 copy + token scores. XCD-pinned.
__global__ __launch_bounds__(256) void prep_kernel(
    const float* __restrict__ emb,      // (B, S, H)
    const float* __restrict__ w,        // (H)
    const float* __restrict__ bias,     // (1)
    const int*   __restrict__ starts,   // (B, N)
    unsigned short* __restrict__ ebf,   // (B, S, H) bf16
    float*       __restrict__ scores,   // (B*S)
    int*         __restrict__ order)    // (B*N)
{
    const int tid = threadIdx.x;

    if ((int)blockIdx.x < 1024) {
        // ---------------- conv part ----------------
        const int wv   = tid >> 6;
        const int lane = tid & 63;
        const int bi   = blockIdx.x & 7;            // example <-> XCD
        const int g    = (int)blockIdx.x >> 3;      // 0..127
        const int t0   = g * 16 + wv * 4;           // 4 rows per wave

        const float* eb = emb + (size_t)bi * SS * HH;
        unsigned short* ob = ebf + (size_t)bi * SS * HH;

        const int h0 = lane * 4;
        const f32x4 w0 = *reinterpret_cast<const f32x4*>(w + h0);
        const f32x4 w1 = *reinterpret_cast<const f32x4*>(w + h0 + 256);
        const f32x4 w2 = *reinterpret_cast<const f32x4*>(w + h0 + 512);
        const float bb = bias[0];

        #pragma unroll
        for (int k = 0; k < 4; ++k) {
            const int t = t0 + k;
            const float* rp = eb + (size_t)t * HH;
            // nontemporal: don't displace ebf lines being written to L2
            f32x4 v0 = __builtin_nontemporal_load(reinterpret_cast<const f32x4*>(rp + h0));
            f32x4 v1 = __builtin_nontemporal_load(reinterpret_cast<const f32x4*>(rp + h0 + 256));
            f32x4 v2 = __builtin_nontemporal_load(reinterpret_cast<const f32x4*>(rp + h0 + 512));

            float d = v0[0]*w0[0] + v0[1]*w0[1] + v0[2]*w0[2] + v0[3]*w0[3]
                    + v1[0]*w1[0] + v1[1]*w1[1] + v1[2]*w1[2] + v1[3]*w1[3]
                    + v2[0]*w2[0] + v2[1]*w2[1] + v2[2]*w2[2] + v2[3]*w2[3];
            #pragma unroll
            for (int off = 32; off; off >>= 1) d += __shfl_xor(d, off);

            uint2 pa, pb, pc;
            pa.x = (unsigned)f2bf(v0[0]) | ((unsigned)f2bf(v0[1]) << 16);
            pa.y = (unsigned)f2bf(v0[2]) | ((unsigned)f2bf(v0[3]) << 16);
            pb.x = (unsigned)f2bf(v1[0]) | ((unsigned)f2bf(v1[1]) << 16);
            pb.y = (unsigned)f2bf(v1[2]) | ((unsigned)f2bf(v1[3]) << 16);
            pc.x = (unsigned)f2bf(v2[0]) | ((unsigned)f2bf(v2[1]) << 16);
            pc.y = (unsigned)f2bf(v2[2]) | ((unsigned)f2bf(v2[3]) << 16);

            unsigned short* op = ob + (size_t)t * HH;
            *reinterpret_cast<uint2*>(op + h0)       = pa;
            *reinterpret_cast<uint2*>(op + h0 + 256) = pb;
            *reinterpret_cast<uint2*>(op + h0 + 512) = pc;

            if (lane == 0) scores[bi * SS + t] = d + bb;
        }
    } else {
        // ---------------- counting sort part ----------------
        const int b = blockIdx.x - 1024;
        __shared__ int hist[SS];
        __shared__ int wsum[4];

        for (int i = tid; i < SS; i += 256) hist[i] = 0;
        __syncthreads();

        const int* st = starts + b * NN;
        for (int n = tid; n < NN; n += 256) atomicAdd(&hist[st[n]], 1);
        __syncthreads();

        const int base = tid * 8;
        int cnt[8]; int s = 0;
        #pragma unroll
        for (int k = 0; k < 8; ++k) { cnt[k] = hist[base + k]; s += cnt[k]; }

        const int lane = tid & 63, wv = tid >> 6;
        int v = s;
        #pragma unroll
        for (int off = 1; off < 64; off <<= 1) {
            int u = __shfl_up(v, off);
            if (lane >= off) v += u;
        }
        if (lane == 63) wsum[wv] = v;
        __syncthreads();
        int wbase = 0;
        #pragma unroll
        for (int k = 0; k < 4; ++k) wbase += (k < wv) ? wsum[k] : 0;

        int excl = wbase + v - s;
        #pragma unroll
        for (int k = 0; k < 8; ++k) { int c = cnt[k]; hist[base + k] = excl; excl += c; }
        __syncthreads();

        for (int n = tid; n < NN; n += 256) {
            int pos = atomicAdd(&hist[st[n]], 1);
            order[b * NN + pos] = n;
        }
    }
}

// ---- Kernel 2: one wave per span, DESCENDING sorted start order (LRU-match).
//      Softmax from precomputed scores, bf16 row sweep, nontemporal out stores.
__global__ __launch_bounds__(256) void span_bf16_kernel(
    const unsigned short* __restrict__ ebf,   // (B, S, H) bf16
    const float* __restrict__ scores,         // (B*S)
    const int*   __restrict__ starts,         // (B, N)
    const int*   __restrict__ lengths,        // (B, N)
    const int*   __restrict__ order,          // (B, N)
    float*       __restrict__ out)            // (B, N, 3H)
{
    const int tid  = threadIdx.x;
    const int wv   = tid >> 6;
    const int lane = tid & 63;
    const int bi   = blockIdx.x & 7;          // example <-> XCD
    const int r    = ((int)blockIdx.x >> 3) * 4 + wv;   // 0..511
    const int rank = NN - 1 - r;              // descending starts
    const int n    = order ? order[bi * NN + rank] : r;
    const int span = bi * NN + n;

    const int start = starts[span];
    const int len   = lengths[span];          // valid t = 0..len (<= 29)

    // ---- softmax up-front: lane t holds p_t ----
    float sc = (lane <= len) ? scores[bi * SS + start + lane] : -INFINITY;
    float m = sc;
    #pragma unroll
    for (int off = 32; off; off >>= 1) m = fmaxf(m, __shfl_xor(m, off));
    float e = (lane <= len) ? __expf(sc - m) : 0.f;
    float sum = e;
    #pragma unroll
    for (int off = 32; off; off >>= 1) sum += __shfl_xor(sum, off);
    const float p = e / sum;

    const unsigned short* rb = ebf + (size_t)bi * SS * HH + (size_t)start * HH;
    const int h0 = lane * 4;
    float* orow = out + (size_t)span * (3 * HH);

    float4 a0 = make_float4(0.f, 0.f, 0.f, 0.f), a1 = a0, a2 = a0;

    // 2-deep prefetch pipeline; no duplicate tail loads
    uint2 cA = *reinterpret_cast<const uint2*>(rb + h0);
    uint2 cB = *reinterpret_cast<const uint2*>(rb + h0 + 256);
    uint2 cC = *reinterpret_cast<const uint2*>(rb + h0 + 512);
    uint2 xA, xB, xC;
    if (len >= 1) {
        const unsigned short* rp1 = rb + HH;
        xA = *reinterpret_cast<const uint2*>(rp1 + h0);
        xB = *reinterpret_cast<const uint2*>(rp1 + h0 + 256);
        xC = *reinterpret_cast<const uint2*>(rp1 + h0 + 512);
    } else { xA = cA; xB = cB; xC = cC; }

    for (int t = 0; t <= len; ++t) {
        uint2 yA, yB, yC;
        if (t + 2 <= len) {
            const unsigned short* rp2 = rb + (size_t)(t + 2) * HH;
            yA = *reinterpret_cast<const uint2*>(rp2 + h0);
            yB = *reinterpret_cast<const uint2*>(rp2 + h0 + 256);
            yC = *reinterpret_cast<const uint2*>(rp2 + h0 + 512);
        } else { yA = cA; yB = cB; yC = cC; }

        const float pt = __shfl(p, t);

        float4 f0, f1, f2;
        f0.x = bflo(cA.x); f0.y = bfhi(cA.x); f0.z = bflo(cA.y); f0.w = bfhi(cA.y);
        f1.x = bflo(cB.x); f1.y = bfhi(cB.x); f1.z = bflo(cB.y); f1.w = bfhi(cB.y);
        f2.x = bflo(cC.x); f2.y = bfhi(cC.x); f2.z = bflo(cC.y); f2.w = bfhi(cC.y);

        a0.x += pt * f0.x; a0.y += pt * f0.y; a0.z += pt * f0.z; a0.w += pt * f0.w;
        a1.x += pt * f1.x; a1.y += pt * f1.y; a1.z += pt * f1.z; a1.w += pt * f1.w;
        a2.x += pt * f2.x; a2.y += pt * f2.y; a2.z += pt * f2.z; a2.w += pt * f2.w;

        if (t == 0) {                    // start row (streaming store)
            __builtin_nontemporal_store(*(const f32x4*)&f0, (f32x4*)(orow + h0));
            __builtin_nontemporal_store(*(const f32x4*)&f1, (f32x4*)(orow + h0 + 256));
            __builtin_nontemporal_store(*(const f32x4*)&f2, (f32x4*)(orow + h0 + 512));
        }
        if (t == len) {                  // end row
            __builtin_nontemporal_store(*(const f32x4*)&f0, (f32x4*)(orow + HH + h0));
            __builtin_nontemporal_store(*(const f32x4*)&f1, (f32x4*)(orow + HH + h0 + 256));
            __builtin_nontemporal_store(*(const f32x4*)&f2, (f32x4*)(orow + HH + h0 + 512));
        }

        cA = xA; cB = xB; cC = xC;
        xA = yA; xB = yB; xC = yC;
    }

    __builtin_nontemporal_store(*(const f32x4*)&a0, (f32x4*)(orow + 2 * HH + h0));
    __builtin_nontemporal_store(*(const f32x4*)&a1, (f32x4*)(orow + 2 * HH + h0 + 256));
    __builtin_nontemporal_store(*(const f32x4*)&a2, (f32x4*)(orow + 2 * HH + h0 + 512));
}

// ---- Fallback (tiny ws): R4's fused fp32 single-pass kernel ----
__global__ __launch_bounds__(256) void span_fused_fp32_kernel(
    const float* __restrict__ emb, const float* __restrict__ w,
    const float* __restrict__ bias, const int* __restrict__ starts,
    const int* __restrict__ lengths, float* __restrict__ out)
{
    const int tid  = threadIdx.x;
    const int wv   = tid >> 6;
    const int lane = tid & 63;
    const int bi   = blockIdx.x & 7;
    const int rank = ((int)blockIdx.x >> 3) * 4 + wv;
    const int span = bi * NN + rank;
    const int start = starts[span];
    const int len   = lengths[span];

    const float* ebase = emb + (size_t)bi * SS * HH + (size_t)start * HH;
    const int h0 = lane * 4;
    float* orow = out + (size_t)span * (3 * HH);

    const float4 w0 = *reinterpret_cast<const float4*>(w + h0);
    const float4 w1 = *reinterpret_cast<const float4*>(w + h0 + 256);
    const float4 w2 = *reinterpret_cast<const float4*>(w + h0 + 512);
    const float bb = bias[0];

    float m = -INFINITY, ssum = 0.f;
    float4 a0 = make_float4(0.f, 0.f, 0.f, 0.f), a1 = a0, a2 = a0;

    const float* row = ebase;
    float4 v0 = *reinterpret_cast<const float4*>(row + h0);
    float4 v1 = *reinterpret_cast<const float4*>(row + h0 + 256);
    float4 v2 = *reinterpret_cast<const float4*>(row + h0 + 512);

    for (int t = 0; t <= len; ++t) {
        float4 n0, n1, n2;
        if (t < len) {
            const float* nr = row + HH;
            n0 = *reinterpret_cast<const float4*>(nr + h0);
            n1 = *reinterpret_cast<const float4*>(nr + h0 + 256);
            n2 = *reinterpret_cast<const float4*>(nr + h0 + 512);
        }
        float d = v0.x * w0.x + v0.y * w0.y + v0.z * w0.z + v0.w * w0.w
                + v1.x * w1.x + v1.y * w1.y + v1.z * w1.z + v1.w * w1.w
                + v2.x * w2.x + v2.y * w2.y + v2.z * w2.z + v2.w * w2.w;
        #pragma unroll
        for (int off = 32; off; off >>= 1) d += __shfl_xor(d, off);
        d += bb;
        if (d > m) {
            const float c = __expf(m - d);
            ssum *= c;
            a0.x *= c; a0.y *= c; a0.z *= c; a0.w *= c;
            a1.x *= c; a1.y *= c; a1.z *= c; a1.w *= c;
            a2.x *= c; a2.y *= c; a2.z *= c; a2.w *= c;
            m = d;
        }
        const float pt = __expf(d - m);
        ssum += pt;
        a0.x += pt * v0.x; a0.y += pt * v0.y; a0.z += pt * v0.z; a0.w += pt * v0.w;
        a1.x += pt * v1.x; a1.y += pt * v1.y; a1.z += pt * v1.z; a1.w += pt * v1.w;
        a2.x += pt * v2.x; a2.y += pt * v2.y; a2.z += pt * v2.z; a2.w += pt * v2.w;
        if (t == 0) {
            *reinterpret_cast<float4*>(orow + h0)       = v0;
            *reinterpret_cast<float4*>(orow + h0 + 256) = v1;
            *reinterpret_cast<float4*>(orow + h0 + 512) = v2;
        }
        if (t == len) {
            *reinterpret_cast<float4*>(orow + HH + h0)       = v0;
            *reinterpret_cast<float4*>(orow + HH + h0 + 256) = v1;
            *reinterpret_cast<float4*>(orow + HH + h0 + 512) = v2;
        }
        v0 = n0; v1 = n1; v2 = n2;
        row += HH;
    }
    const float inv = 1.f / ssum;
    a0.x *= inv; a0.y *= inv; a0.z *= inv; a0.w *= inv;
    a1.x *= inv; a1.y *= inv; a1.z *= inv; a1.w *= inv;
    a2.x *= inv; a2.y *= inv; a2.z *= inv; a2.w *= inv;
    *reinterpret_cast<float4*>(orow + 2 * HH + h0)       = a0;
    *reinterpret_cast<float4*>(orow + 2 * HH + h0 + 256) = a1;
    *reinterpret_cast<float4*>(orow + 2 * HH + h0 + 512) = a2;
}

extern "C" void kernel_launch(void* const* d_in, const int* in_sizes, int n_in,
                              void* d_out, int out_size, void* d_ws, size_t ws_size,
                              hipStream_t stream) {
    const float* emb     = (const float*)d_in[0];
    const float* w       = (const float*)d_in[1];
    const float* bias    = (const float*)d_in[2];
    const int*   starts  = (const int*)d_in[3];
    const int*   lengths = (const int*)d_in[4];
    float*       out     = (float*)d_out;

    const size_t ebf_bytes    = (size_t)BB * SS * HH * sizeof(unsigned short);
    const size_t scores_bytes = (size_t)BB * SS * sizeof(float);
    const size_t order_bytes  = (size_t)BB * NN * sizeof(int);

    if (ws_size >= ebf_bytes + scores_bytes + order_bytes) {
        unsigned short* ebf = (unsigned short*)d_ws;
        float* scores = (float*)((char*)d_ws + ebf_bytes);
        int*   order  = (int*)((char*)d_ws + ebf_bytes + scores_bytes);

        prep_kernel<<<dim3(1024 + BB), dim3(256), 0, stream>>>(
            emb, w, bias, starts, ebf, scores, order);
        span_bf16_kernel<<<dim3(BB * NN / 4), dim3(256), 0, stream>>>(
            ebf, scores, starts, lengths, order, out);
    } else {
        span_fused_fp32_kernel<<<dim3(BB * NN / 4), dim3(256), 0, stream>>>(
            emb, w, bias, starts, lengths, out);
    }
}